// Round 2
// baseline (379.782 us; speedup 1.0000x reference)
//
#include <hip/hip_runtime.h>
#include <math.h>

// x (8, 96, 256, 256) fp32; K=3, pad=1, stride=1.
//   pooled = mean(x, axis=(2,3)); hid = relu(pooled@w1.T+b1);
//   kw = softmax(hid@w2.T+b2)  (8,9)
//   out[b,c,i,j] = sum_{di,dj} kw[b,di*3+dj] * x_pad[b,c,i+di-1,j+dj-1]
//
// Structure (round 2): TWO kernels.
//   K1 pool: quarter-plane partial means (pre-scaled by 1/PLANE).
//   K2 conv: per-block LDS prologue recomputes the tiny attention MLP for its
//            batch (reads partials written by K1; kernel boundary = coherence),
//            then rolling-row 3x3 depthwise conv, 32-row wave strips (1.06x halo),
//            1-row global prefetch, NT stores (keep x resident in L3 for reads).

#define NB 8
#define NC 96
#define HH 256
#define WW 256
#define PLANE (HH * WW)
#define NPLANES (NB * NC)

typedef float vfloat4 __attribute__((ext_vector_type(4)));  // clang-native, NT-store OK

// ---------------- Kernel 1: global average pool (quarter-plane partials) ----------------
__global__ __launch_bounds__(256) void pool_kernel(const float* __restrict__ x,
                                                   float* __restrict__ partial) {
    const int blk = blockIdx.x;          // 0..3071 ; plane = blk>>2, quarter = blk&3
    const int tid = threadIdx.x;
    const vfloat4* xp = (const vfloat4*)x + (size_t)(blk >> 2) * (PLANE / 4)
                        + (size_t)(blk & 3) * 4096;
    float s = 0.f;
#pragma unroll
    for (int k = 0; k < 16; ++k) {
        vfloat4 v = xp[k * 256 + tid];
        s += (v.x + v.y) + (v.z + v.w);
    }
#pragma unroll
    for (int off = 32; off > 0; off >>= 1) s += __shfl_down(s, off);
    __shared__ float ws[4];
    if ((tid & 63) == 0) ws[tid >> 6] = s;
    __syncthreads();
    if (tid == 0)
        partial[blk] = ((ws[0] + ws[1]) + (ws[2] + ws[3])) * (1.0f / (float)PLANE);
}

// ---------------- Kernel 2: MLP prologue + rolling-row dynamic 3x3 depthwise conv ----
struct Row {
    vfloat4 v;
    float hl, hr;  // col jc-1 (from lane-1) and col jc+4 (from lane+1)
};

__device__ __forceinline__ vfloat4 raw_row(const float* __restrict__ xpl, int r,
                                           int lane) {
    if ((unsigned)r < (unsigned)HH)
        return *(const vfloat4*)(xpl + (size_t)r * WW + (lane << 2));
    return (vfloat4){0.f, 0.f, 0.f, 0.f};  // zero pad rows -1 / 256 (wave-uniform r)
}

__device__ __forceinline__ Row make_row(vfloat4 v, int lane) {
    Row r;
    r.v = v;
    float up = __shfl_up(v.w, 1);
    float dn = __shfl_down(v.x, 1);
    r.hl = (lane == 0) ? 0.f : up;   // zero pad at j = -1
    r.hr = (lane == 63) ? 0.f : dn;  // zero pad at j = 256
    return r;
}

__device__ __forceinline__ void row_fma(const Row& r, float wl, float wc, float wr,
                                        vfloat4& o) {
    o.x = fmaf(wl, r.hl,  fmaf(wc, r.v.x, fmaf(wr, r.v.y, o.x)));
    o.y = fmaf(wl, r.v.x, fmaf(wc, r.v.y, fmaf(wr, r.v.z, o.y)));
    o.z = fmaf(wl, r.v.y, fmaf(wc, r.v.z, fmaf(wr, r.v.w, o.z)));
    o.w = fmaf(wl, r.v.z, fmaf(wc, r.v.w, fmaf(wr, r.hr,  o.w)));
}

// grid: (2 strips-of-4-waves, 96 channels, 8 batches); block 256 = 4 waves,
// each wave a 32-row strip. Per wave: 34 rows loaded / 32 produced (1.06x).
__global__ __launch_bounds__(256) void conv_kernel(const float* __restrict__ x,
                                                   const float* __restrict__ partial,
                                                   const float* __restrict__ w1,
                                                   const float* __restrict__ b1,
                                                   const float* __restrict__ w2,
                                                   const float* __restrict__ b2,
                                                   float* __restrict__ out) {
    const int tid = threadIdx.x;
    const int batch = blockIdx.z;

    // ---- attention MLP prologue (block-redundant, ~1 us, replaces attn kernel) ----
    __shared__ float pld[NC];
    __shared__ float hid[12];
    __shared__ float lg[9];
    __shared__ float kwS[9];
    if (tid < NC) {
        const float* pp = partial + ((size_t)(batch * NC + tid) << 2);
        pld[tid] = (pp[0] + pp[1]) + (pp[2] + pp[3]);   // already scaled by 1/PLANE
    }
    __syncthreads();
    if (tid < 12) {
        float a = b1[tid];
#pragma unroll
        for (int c = 0; c < NC; ++c) a = fmaf(pld[c], w1[tid * NC + c], a);
        hid[tid] = a > 0.f ? a : 0.f;
    }
    __syncthreads();
    if (tid < 9) {
        float a = b2[tid];
#pragma unroll
        for (int j = 0; j < 12; ++j) a = fmaf(hid[j], w2[tid * 12 + j], a);
        lg[tid] = a;
    }
    __syncthreads();
    if (tid == 0) {
        float m = lg[0];
#pragma unroll
        for (int q = 1; q < 9; ++q) m = fmaxf(m, lg[q]);
        float e[9], s = 0.f;
#pragma unroll
        for (int q = 0; q < 9; ++q) { e[q] = __expf(lg[q] - m); s += e[q]; }
        float inv = 1.f / s;
#pragma unroll
        for (int q = 0; q < 9; ++q) kwS[q] = e[q] * inv;
    }
    __syncthreads();

    float w[9];
#pragma unroll
    for (int p = 0; p < 9; ++p) w[p] = kwS[p];  // wave-uniform LDS broadcast

    // ---- rolling-row conv ----
    const int lane = tid & 63;
    const int strip = (blockIdx.x << 2) + (tid >> 6);  // 0..7
    const int rs = strip << 5;                         // first output row

    const size_t base = ((size_t)(batch * NC + blockIdx.y)) * PLANE;
    const float* xpl = x + base;
    float* opl = out + base;

    Row a = make_row(raw_row(xpl, rs - 1, lane), lane);
    Row b = make_row(raw_row(xpl, rs, lane), lane);
    vfloat4 pre = raw_row(xpl, rs + 1, lane);  // row rs+1, shuffles deferred

#pragma unroll 4
    for (int i = rs; i < rs + 32; ++i) {
        // issue next raw load first (independent address) -> a full iteration of
        // FMAs + store sits between the load and its vmcnt wait next iteration
        vfloat4 nxt = (i + 2 <= rs + 32) ? raw_row(xpl, i + 2, lane)
                                         : (vfloat4){0.f, 0.f, 0.f, 0.f};
        Row c = make_row(pre, lane);
        vfloat4 o = (vfloat4){0.f, 0.f, 0.f, 0.f};
        row_fma(a, w[0], w[1], w[2], o);
        row_fma(b, w[3], w[4], w[5], o);
        row_fma(c, w[6], w[7], w[8], o);
        __builtin_nontemporal_store(o, (vfloat4*)(opl + (size_t)i * WW + (lane << 2)));
        a = b; b = c; pre = nxt;
    }
}

extern "C" void kernel_launch(void* const* d_in, const int* in_sizes, int n_in,
                              void* d_out, int out_size, void* d_ws, size_t ws_size,
                              hipStream_t stream) {
    const float* x  = (const float*)d_in[0];
    const float* w1 = (const float*)d_in[1];
    const float* b1 = (const float*)d_in[2];
    const float* w2 = (const float*)d_in[3];
    const float* b2 = (const float*)d_in[4];
    float* out = (float*)d_out;

    float* partial = (float*)d_ws;  // 3072 floats (4 pre-scaled partials per plane)

    pool_kernel<<<NPLANES * 4, 256, 0, stream>>>(x, partial);
    dim3 grid(2, NC, NB);           // 1536 blocks, 6/CU, 24 waves/CU
    conv_kernel<<<grid, 256, 0, stream>>>(x, partial, w1, b1, w2, b2, out);
}